// Round 1
// baseline (1435.636 us; speedup 1.0000x reference)
//
#include <hip/hip_runtime.h>
#include <math.h>

// Problem constants (B, CK, CV, T, H, W) = (2, 64, 256, 8, 48, 48)
#define NB 2
#define CKD 64
#define CVD 256
#define TD 8
#define HWD 2304
#define THWD 18432
#define NT 64              // query tile (n)
#define NTILES (HWD / NT)  // 36
#define TT 16              // key tile (t)

// ---------------------------------------------------------------------------
// prep: qh2[b][c][n] = 2*qk*qe ; bsq[b][n] = sum_c qe*qk*qk
// ---------------------------------------------------------------------------
__global__ void prep_kernel(const float* __restrict__ qk,
                            const float* __restrict__ qe,
                            float* __restrict__ qh2,
                            float* __restrict__ bsq) {
    int idx = blockIdx.x * 256 + threadIdx.x;
    if (idx >= NB * HWD) return;
    int b = idx / HWD, n = idx % HWD;
    const float* qkb = qk + (size_t)b * CKD * HWD + n;
    const float* qeb = qe + (size_t)b * CKD * HWD + n;
    float* qhb = qh2 + (size_t)b * CKD * HWD + n;
    float s = 0.f;
#pragma unroll 8
    for (int c = 0; c < CKD; ++c) {
        float k = qkb[(size_t)c * HWD];
        float e = qeb[(size_t)c * HWD];
        qhb[(size_t)c * HWD] = 2.f * k * e;
        s = fmaf(e * k, k, s);
    }
    bsq[idx] = s;
}

// ---------------------------------------------------------------------------
// fused: scores -> exp (no max needed: scores <= 0) -> partial l and
// partial acc[cv][n] over this block's t-range. Split-T partials are pure
// sums (no softmax max bookkeeping required).
// Block: 256 threads. Tile: NT=64 queries x full CV=256, loop t in TT=16.
// ---------------------------------------------------------------------------
__global__ __launch_bounds__(256, 2) void fused_kernel(
    const float* __restrict__ mk,    // [B][CK][THW]
    const float* __restrict__ ms,    // [B][THW]
    const float* __restrict__ mv,    // [B][CV][THW]
    const float* __restrict__ qe,    // [B][CK][HW]
    const float* __restrict__ qh2,   // [B][CK][HW]
    const float* __restrict__ bsq,   // [B][HW]
    float* __restrict__ accP,        // [B*NTILES*nsplit][CV*NT]
    float* __restrict__ lP,          // [B*NTILES*nsplit][NT]
    int nsplit, int tiles_per_split) {
    __shared__ float qe_s[CKD][NT];   // 16 KB
    __shared__ float qh_s[CKD][NT];   // 16 KB
    __shared__ float mk_s[CKD][TT];   // 4 KB
    __shared__ float mv_s[TT][CVD];   // 16 KB (t-major for b128 PV reads)
    __shared__ float w_s[TT][NT];     // 4 KB
    __shared__ float ms_s[TT];
    __shared__ float bsq_s[NT];

    const int tid = threadIdx.x;
    const int ntile = blockIdx.x;
    const int split = blockIdx.y;
    const int b = blockIdx.z;
    const int n0 = ntile * NT;

    // Stage per-block query panels (reused across all t tiles)
    {
        int c = tid >> 2, off = (tid & 3) * 16;
        const float* s1 = qe + (size_t)b * CKD * HWD + (size_t)c * HWD + n0 + off;
        const float* s2 = qh2 + (size_t)b * CKD * HWD + (size_t)c * HWD + n0 + off;
        float4* d1 = (float4*)&qe_s[c][off];
        float4* d2 = (float4*)&qh_s[c][off];
#pragma unroll
        for (int j = 0; j < 4; ++j) {
            d1[j] = ((const float4*)s1)[j];
            d2[j] = ((const float4*)s2)[j];
        }
    }
    if (tid < NT) bsq_s[tid] = bsq[b * HWD + n0 + tid];

    float acc[16][4];
#pragma unroll
    for (int i = 0; i < 16; ++i)
#pragma unroll
        for (int j = 0; j < 4; ++j) acc[i][j] = 0.f;
    float lreg[4] = {0.f, 0.f, 0.f, 0.f};

    const float* mkb = mk + (size_t)b * CKD * THWD;
    const float* mvb = mv + (size_t)b * CVD * THWD;
    const float* msb = ms + (size_t)b * THWD;

    const int tx = tid & 15;  // n-group (PV) / t index (score)
    const int ty = tid >> 4;  // cv-group (PV) / n-group (score)

    const int t_begin = split * tiles_per_split * TT;

    for (int it = 0; it < tiles_per_split; ++it) {
        const int t0 = t_begin + it * TT;
        __syncthreads();  // protect mk_s/mv_s/w_s from previous iteration readers
        // stage mk tile (64c x 16t)
        {
            int c = tid >> 2, seg = tid & 3;
            *(float4*)&mk_s[c][seg * 4] =
                *(const float4*)(mkb + (size_t)c * THWD + t0 + seg * 4);
        }
        if (tid < TT) ms_s[tid] = msb[t0 + tid];
        // stage mv tile transposed into mv_s[t][cv]
        {
            int cvr = tid >> 2, seg = tid & 3;
#pragma unroll
            for (int pass = 0; pass < 4; ++pass) {
                int cv = pass * 64 + cvr;
                float4 v = *(const float4*)(mvb + (size_t)cv * THWD + t0 + seg * 4);
                mv_s[seg * 4 + 0][cv] = v.x;
                mv_s[seg * 4 + 1][cv] = v.y;
                mv_s[seg * 4 + 2][cv] = v.z;
                mv_s[seg * 4 + 3][cv] = v.w;
            }
        }
        __syncthreads();
        // scores: thread (st=tx, sg=ty) computes w for (t = t0+tx, n = n0+ty*4..+3)
        {
            float d0 = 0.f, d1 = 0.f, d2 = 0.f, d3 = 0.f;
#pragma unroll 16
            for (int c = 0; c < CKD; ++c) {
                float k = mk_s[c][tx];
                float4 e = *(const float4*)&qe_s[c][ty * 4];
                float4 h = *(const float4*)&qh_s[c][ty * 4];
                d0 = fmaf(k, fmaf(-k, e.x, h.x), d0);
                d1 = fmaf(k, fmaf(-k, e.y, h.y), d1);
                d2 = fmaf(k, fmaf(-k, e.z, h.z), d2);
                d3 = fmaf(k, fmaf(-k, e.w, h.w), d3);
            }
            float m = ms_s[tx] * 0.125f;
            float4 bq = *(const float4*)&bsq_s[ty * 4];
            float4 wv;
            wv.x = __expf((d0 - bq.x) * m);
            wv.y = __expf((d1 - bq.y) * m);
            wv.z = __expf((d2 - bq.z) * m);
            wv.w = __expf((d3 - bq.w) * m);
            *(float4*)&w_s[tx][ty * 4] = wv;
        }
        __syncthreads();
        // PV: thread (tx, ty) owns n = n0+tx*4..+3, cv = ty*16..+15
#pragma unroll 4
        for (int t = 0; t < TT; ++t) {
            float4 w = *(const float4*)&w_s[t][tx * 4];
            if (ty == 0) {
                lreg[0] += w.x; lreg[1] += w.y; lreg[2] += w.z; lreg[3] += w.w;
            }
            const float4* mvrow = (const float4*)&mv_s[t][ty * 16];
#pragma unroll
            for (int k4 = 0; k4 < 4; ++k4) {
                float4 v = mvrow[k4];
                acc[k4 * 4 + 0][0] = fmaf(v.x, w.x, acc[k4 * 4 + 0][0]);
                acc[k4 * 4 + 0][1] = fmaf(v.x, w.y, acc[k4 * 4 + 0][1]);
                acc[k4 * 4 + 0][2] = fmaf(v.x, w.z, acc[k4 * 4 + 0][2]);
                acc[k4 * 4 + 0][3] = fmaf(v.x, w.w, acc[k4 * 4 + 0][3]);
                acc[k4 * 4 + 1][0] = fmaf(v.y, w.x, acc[k4 * 4 + 1][0]);
                acc[k4 * 4 + 1][1] = fmaf(v.y, w.y, acc[k4 * 4 + 1][1]);
                acc[k4 * 4 + 1][2] = fmaf(v.y, w.z, acc[k4 * 4 + 1][2]);
                acc[k4 * 4 + 1][3] = fmaf(v.y, w.w, acc[k4 * 4 + 1][3]);
                acc[k4 * 4 + 2][0] = fmaf(v.z, w.x, acc[k4 * 4 + 2][0]);
                acc[k4 * 4 + 2][1] = fmaf(v.z, w.y, acc[k4 * 4 + 2][1]);
                acc[k4 * 4 + 2][2] = fmaf(v.z, w.z, acc[k4 * 4 + 2][2]);
                acc[k4 * 4 + 2][3] = fmaf(v.z, w.w, acc[k4 * 4 + 2][3]);
                acc[k4 * 4 + 3][0] = fmaf(v.w, w.x, acc[k4 * 4 + 3][0]);
                acc[k4 * 4 + 3][1] = fmaf(v.w, w.y, acc[k4 * 4 + 3][1]);
                acc[k4 * 4 + 3][2] = fmaf(v.w, w.z, acc[k4 * 4 + 3][2]);
                acc[k4 * 4 + 3][3] = fmaf(v.w, w.w, acc[k4 * 4 + 3][3]);
            }
        }
    }

    // write partials
    size_t pbase = ((size_t)((b * NTILES + ntile) * nsplit + split)) * (CVD * NT);
#pragma unroll
    for (int k = 0; k < 16; ++k) {
        int cv = ty * 16 + k;
        *(float4*)(accP + pbase + (size_t)cv * NT + tx * 4) =
            make_float4(acc[k][0], acc[k][1], acc[k][2], acc[k][3]);
    }
    if (ty == 0) {
        size_t lbase = ((size_t)((b * NTILES + ntile) * nsplit + split)) * NT;
        *(float4*)(lP + lbase + tx * 4) =
            make_float4(lreg[0], lreg[1], lreg[2], lreg[3]);
    }
}

// ---------------------------------------------------------------------------
// combine: sum split partials, divide, blend with last frame.
// out[b][cv][n] = (sum_s acc / sum_s l) * p + last * (1 - p)
// ---------------------------------------------------------------------------
__global__ void combine_kernel(const float* __restrict__ accP,
                               const float* __restrict__ lP,
                               const float* __restrict__ mv,
                               const float* __restrict__ uncert,
                               float* __restrict__ out, int nsplit) {
    int idx = blockIdx.x * 256 + threadIdx.x;
    if (idx >= NB * CVD * HWD) return;
    int n = idx % HWD;
    int cv = (idx / HWD) % CVD;
    int b = idx / (HWD * CVD);
    int ntile = n / NT, nl = n % NT;
    size_t base =
        ((size_t)(b * NTILES + ntile) * nsplit) * (CVD * NT) + (size_t)cv * NT + nl;
    size_t lb = ((size_t)(b * NTILES + ntile) * nsplit) * NT + nl;
    float a = 0.f, l = 0.f;
    for (int s = 0; s < nsplit; ++s) {
        a += accP[base + (size_t)s * CVD * NT];
        l += lP[lb + (size_t)s * NT];
    }
    float readout = a / l;
    float p = uncert[b * HWD + n];
    float last = mv[((size_t)b * CVD + cv) * THWD + (TD - 1) * HWD + n];
    out[idx] = readout * p + last * (1.f - p);
}

// ---------------------------------------------------------------------------
extern "C" void kernel_launch(void* const* d_in, const int* in_sizes, int n_in,
                              void* d_out, int out_size, void* d_ws,
                              size_t ws_size, hipStream_t stream) {
    const float* qk = (const float*)d_in[0];  // query_key      [B,CK,H,W]
    const float* qe = (const float*)d_in[1];  // query_selection[B,CK,H,W]
    const float* mk = (const float*)d_in[2];  // memory_key     [B,CK,T,H,W]
    const float* ms = (const float*)d_in[3];  // memory_shrink  [B,1,T,H,W]
    const float* mv = (const float*)d_in[4];  // msk_value      [B,1,CV,T,H,W]
    const float* up = (const float*)d_in[5];  // uncert_prob    [B,1,H,W]
    float* out = (float*)d_out;

    float* ws = (float*)d_ws;
    size_t qh2_off = 0;
    size_t bsq_off = qh2_off + (size_t)NB * CKD * HWD;
    size_t fixed = bsq_off + (size_t)NB * HWD;

    // choose split count that fits the workspace (powers of two divide 1152 tiles)
    int nsplit = 8;
    while (nsplit > 1) {
        size_t need = fixed + (size_t)NB * NTILES * nsplit * (NT + (size_t)CVD * NT);
        if (need * sizeof(float) <= ws_size) break;
        nsplit >>= 1;
    }
    size_t lP_off = fixed;
    size_t acc_off = lP_off + (size_t)NB * NTILES * nsplit * NT;

    float* qh2 = ws + qh2_off;
    float* bsq = ws + bsq_off;
    float* lPp = ws + lP_off;
    float* accPp = ws + acc_off;

    int tiles_per_split = (THWD / TT) / nsplit;  // 1152 / nsplit

    prep_kernel<<<(NB * HWD + 255) / 256, 256, 0, stream>>>(qk, qe, qh2, bsq);

    dim3 grid(NTILES, nsplit, NB);
    fused_kernel<<<grid, 256, 0, stream>>>(mk, ms, mv, qe, qh2, bsq, accPp, lPp,
                                           nsplit, tiles_per_split);

    combine_kernel<<<(NB * CVD * HWD + 255) / 256, 256, 0, stream>>>(
        accPp, lPp, mv, up, out, nsplit);
}

// Round 2
// 382.107 us; speedup vs baseline: 3.7572x; 3.7572x over previous
//
#include <hip/hip_runtime.h>
#include <math.h>

// (B, CK, CV, T, H, W) = (2, 64, 256, 8, 48, 48)
#define NB 2
#define CKD 64
#define CVD 256
#define TD 8
#define HWD 2304
#define THWD 18432
#define QB 128             // queries per block
#define NQB (HWD / QB)     // 18
#define KVB 64             // keys per tile

typedef __bf16 bf16_t;
typedef __bf16 bf16x8 __attribute__((ext_vector_type(8)));
typedef __bf16 bf16x4 __attribute__((ext_vector_type(4)));
typedef float f32x4 __attribute__((ext_vector_type(4)));

// ---------------------------------------------------------------------------
// prep_kf: KF[b][t][c] = mk (c<64) | mk^2 (c>=64), bf16, row-major [t][128].
// LDS tile-transpose so both sides are coalesced.
// ---------------------------------------------------------------------------
__global__ void prep_kf(const float* __restrict__ mk, bf16_t* __restrict__ KF) {
    __shared__ float tile[64][65];
    const int b = blockIdx.y;
    const int t0 = blockIdx.x * 64;
    const int tid = threadIdx.x;
    {
        const int c = tid >> 2, seg = tid & 3;
        const float* src = mk + ((size_t)b * CKD + c) * THWD + t0;
#pragma unroll
        for (int j = 0; j < 4; ++j) {
            int ch = seg + j * 4;  // 0..15
            f32x4 v = *(const f32x4*)(src + ch * 4);
#pragma unroll
            for (int x = 0; x < 4; ++x) tile[c][ch * 4 + x] = v[x];
        }
    }
    __syncthreads();
    const int tl = tid >> 2, part = tid & 3;
    bf16_t* dst = KF + ((size_t)b * THWD + t0 + tl) * 128;
#pragma unroll
    for (int pk = 0; pk < 4; ++pk) {
        bf16x8 pkt;
#pragma unroll
        for (int e = 0; e < 8; ++e) {
            int cc = pk * 32 + part * 8 + e;
            float v;
            if (cc < 64) {
                v = tile[cc][tl];
            } else {
                float m = tile[cc - 64][tl];
                v = m * m;
            }
            pkt[e] = (bf16_t)v;
        }
        *(bf16x8*)(dst + pk * 32 + part * 8) = pkt;
    }
}

// ---------------------------------------------------------------------------
// prep_qf: QF[b][n][c] = 2*qk*qe (c<64) | -qe (c>=64), bf16 [n][128];
// bsq[b][n] = sum_c qe*qk*qk (fp32).
// ---------------------------------------------------------------------------
__global__ void prep_qf(const float* __restrict__ qk, const float* __restrict__ qe,
                        bf16_t* __restrict__ QF, float* __restrict__ bsq) {
    __shared__ float tk[64][65];
    __shared__ float te[64][65];
    const int b = blockIdx.y;
    const int n0 = blockIdx.x * 64;
    const int tid = threadIdx.x;
    {
        const int c = tid >> 2, seg = tid & 3;
        const float* s1 = qk + ((size_t)b * CKD + c) * HWD + n0;
        const float* s2 = qe + ((size_t)b * CKD + c) * HWD + n0;
#pragma unroll
        for (int j = 0; j < 4; ++j) {
            int ch = seg + j * 4;
            f32x4 v1 = *(const f32x4*)(s1 + ch * 4);
            f32x4 v2 = *(const f32x4*)(s2 + ch * 4);
#pragma unroll
            for (int x = 0; x < 4; ++x) {
                tk[c][ch * 4 + x] = v1[x];
                te[c][ch * 4 + x] = v2[x];
            }
        }
    }
    __syncthreads();
    const int nl = tid >> 2, part = tid & 3;
    bf16_t* dst = QF + ((size_t)b * HWD + n0 + nl) * 128;
    float bpart = 0.f;
#pragma unroll
    for (int pk = 0; pk < 4; ++pk) {
        bf16x8 pkt;
#pragma unroll
        for (int e = 0; e < 8; ++e) {
            int cc = pk * 32 + part * 8 + e;
            float v;
            if (cc < 64) {
                float k = tk[cc][nl], s = te[cc][nl];
                v = 2.f * k * s;
                bpart = fmaf(s * k, k, bpart);
            } else {
                v = -te[cc - 64][nl];
            }
            pkt[e] = (bf16_t)v;
        }
        *(bf16x8*)(dst + pk * 32 + part * 8) = pkt;
    }
    // combine 4 partial c-ranges (lanes differing in bits 0-1 share tl)
    bpart += __shfl_xor(bpart, 1);
    bpart += __shfl_xor(bpart, 2);
    if (part == 0) bsq[b * HWD + n0 + nl] = bpart;
}

// ---------------------------------------------------------------------------
// mv_cvt: fp32 -> bf16 elementwise for msk_value
// ---------------------------------------------------------------------------
__global__ void mv_cvt(const float* __restrict__ mv, bf16_t* __restrict__ mvb) {
    size_t i = ((size_t)blockIdx.x * 256 + threadIdx.x) * 4;
    if (i >= (size_t)NB * CVD * THWD) return;
    f32x4 v = *(const f32x4*)(mv + i);
    bf16x4 o;
    o[0] = (bf16_t)v[0]; o[1] = (bf16_t)v[1];
    o[2] = (bf16_t)v[2]; o[3] = (bf16_t)v[3];
    *(bf16x4*)(mvb + i) = o;
}

// ---------------------------------------------------------------------------
// fused flash kernel: 512 threads (8 waves = 2 cv-halves x 4 q-groups).
// Per KV-tile (64 keys): QK MFMA (K=128) -> exp -> w_s (swizzled bf16) -> PV MFMA.
// A-frags (KF rows / mv rows) straight from global; QF B-frags in registers.
// ---------------------------------------------------------------------------
__global__ __launch_bounds__(512, 2) void fused(
    const bf16_t* __restrict__ KF, const bf16_t* __restrict__ QF,
    const bf16_t* __restrict__ mvb, const float* __restrict__ ms,
    const float* __restrict__ bsq, float* __restrict__ accP,
    float* __restrict__ lP, int split, int tiles) {
    __shared__ __align__(16) char wsm[QB * 128];  // [128 q][64 kv] bf16, XOR-swizzled
    __shared__ float l_s[2][QB];

    const int tid = threadIdx.x;
    const int lane = tid & 63;
    const int wave = tid >> 6;   // 0..7
    const int wq = wave & 3;     // q-group: q in [wq*32, wq*32+32)
    const int wc = wave >> 2;    // cv-half: cv in [wc*128, wc*128+128)
    const int r = lane & 15;
    const int g = lane >> 4;

    const int qblk = blockIdx.x;
    const int sp = blockIdx.y;
    const int b = blockIdx.z;
    const int tbase = sp * (THWD / split);

    const bf16_t* KFb = KF + (size_t)b * THWD * 128;
    const bf16_t* QFb = QF + (size_t)b * HWD * 128;
    const bf16_t* mvbb = mvb + (size_t)b * CVD * THWD;
    const float* msb = ms + (size_t)b * THWD;

    const f32x4 fzero = {0.f, 0.f, 0.f, 0.f};

    // resident query B-frags + bsq
    bf16x8 qf[2][4];
    float bsqr[2];
#pragma unroll
    for (int ql = 0; ql < 2; ++ql) {
        int qrow = qblk * QB + (wq * 2 + ql) * 16 + r;
#pragma unroll
        for (int ks = 0; ks < 4; ++ks)
            qf[ql][ks] = *(const bf16x8*)(QFb + (size_t)qrow * 128 + ks * 32 + g * 8);
        bsqr[ql] = bsq[b * HWD + qrow];
    }

    f32x4 acc[8][2];
#pragma unroll
    for (int i = 0; i < 8; ++i)
#pragma unroll
        for (int j = 0; j < 2; ++j) acc[i][j] = fzero;
    float lacc[2] = {0.f, 0.f};

    for (int it = 0; it < tiles; ++it) {
        const int t0 = tbase + it * KVB;
        // prefetch PV A-frags (mv) — latency hidden under QK phase
        bf16x8 mvf[2][8];
#pragma unroll
        for (int ks = 0; ks < 2; ++ks)
#pragma unroll
            for (int cvt = 0; cvt < 8; ++cvt) {
                int cvrow = wc * 128 + cvt * 16 + r;
                mvf[ks][cvt] = *(const bf16x8*)(mvbb + (size_t)cvrow * THWD + t0 +
                                                ks * 32 + g * 8);
            }
        // ms (per-key scale)
        f32x4 msv[2];
#pragma unroll
        for (int kl = 0; kl < 2; ++kl)
            msv[kl] = *(const f32x4*)(msb + t0 + (wc * 2 + kl) * 16 + g * 4);

        // QK: S[kv 32-strip of this wave][q 32-range of this wave]
        f32x4 S[2][2];
#pragma unroll
        for (int kl = 0; kl < 2; ++kl)
#pragma unroll
            for (int ql = 0; ql < 2; ++ql) S[kl][ql] = fzero;
#pragma unroll
        for (int ks = 0; ks < 4; ++ks) {
            bf16x8 kff[2];
#pragma unroll
            for (int kl = 0; kl < 2; ++kl) {
                int kvrow = t0 + (wc * 2 + kl) * 16 + r;
                kff[kl] = *(const bf16x8*)(KFb + (size_t)kvrow * 128 + ks * 32 + g * 8);
            }
#pragma unroll
            for (int kl = 0; kl < 2; ++kl)
#pragma unroll
                for (int ql = 0; ql < 2; ++ql)
                    S[kl][ql] = __builtin_amdgcn_mfma_f32_16x16x32_bf16(
                        kff[kl], qf[ql][ks], S[kl][ql], 0, 0, 0);
        }

        // w = exp((dot - bsq) * ms/8), accumulate l, pack bf16
        bf16x4 wv[2][2];
#pragma unroll
        for (int kl = 0; kl < 2; ++kl)
#pragma unroll
            for (int ql = 0; ql < 2; ++ql) {
                f32x4 s = S[kl][ql];
                float w0 = __expf((s[0] - bsqr[ql]) * (msv[kl][0] * 0.125f));
                float w1 = __expf((s[1] - bsqr[ql]) * (msv[kl][1] * 0.125f));
                float w2 = __expf((s[2] - bsqr[ql]) * (msv[kl][2] * 0.125f));
                float w3 = __expf((s[3] - bsqr[ql]) * (msv[kl][3] * 0.125f));
                lacc[ql] += (w0 + w1) + (w2 + w3);
                bf16x4 wb;
                wb[0] = (bf16_t)w0; wb[1] = (bf16_t)w1;
                wb[2] = (bf16_t)w2; wb[3] = (bf16_t)w3;
                wv[kl][ql] = wb;
            }

        __syncthreads();  // previous PV done reading w_s
#pragma unroll
        for (int kl = 0; kl < 2; ++kl)
#pragma unroll
            for (int ql = 0; ql < 2; ++ql) {
                int q = wq * 32 + ql * 16 + r;
                int kvbyte = ((wc * 2 + kl) * 16 + g * 4) * 2;
                *(bf16x4*)(wsm + q * 128 + ((kvbyte & ~15) ^ ((q & 7) << 4)) +
                           (kvbyte & 15)) = wv[kl][ql];
            }
        __syncthreads();  // w_s ready

        // PV: acc[cv][q] += mv[cv][kv] * w[kv][q]
        bf16x8 wf[2][2];
#pragma unroll
        for (int ks = 0; ks < 2; ++ks)
#pragma unroll
            for (int ql = 0; ql < 2; ++ql) {
                int q = wq * 32 + ql * 16 + r;
                int kvbyte = (ks * 32 + g * 8) * 2;
                wf[ks][ql] = *(const bf16x8*)(wsm + q * 128 +
                                              ((kvbyte & ~15) ^ ((q & 7) << 4)));
            }
#pragma unroll
        for (int ks = 0; ks < 2; ++ks)
#pragma unroll
            for (int cvt = 0; cvt < 8; ++cvt)
#pragma unroll
                for (int ql = 0; ql < 2; ++ql)
                    acc[cvt][ql] = __builtin_amdgcn_mfma_f32_16x16x32_bf16(
                        mvf[ks][cvt], wf[ks][ql], acc[cvt][ql], 0, 0, 0);
    }

    // epilogue: write partial acc / l
    size_t pb = (size_t)(b * NQB + qblk) * split + sp;
    float* accB = accP + pb * (CVD * QB);
#pragma unroll
    for (int cvt = 0; cvt < 8; ++cvt)
#pragma unroll
        for (int ql = 0; ql < 2; ++ql) {
            int q = wq * 32 + ql * 16 + r;
#pragma unroll
            for (int i = 0; i < 4; ++i) {
                int cv = wc * 128 + cvt * 16 + g * 4 + i;
                accB[(size_t)cv * QB + q] = acc[cvt][ql][i];
            }
        }
#pragma unroll
    for (int ql = 0; ql < 2; ++ql) {
        float v = lacc[ql];
        v += __shfl_xor(v, 16);
        v += __shfl_xor(v, 32);
        if (lane < 16) l_s[wc][wq * 32 + ql * 16 + lane] = v;
    }
    __syncthreads();
    if (tid < QB) lP[pb * QB + tid] = l_s[0][tid] + l_s[1][tid];
}

// ---------------------------------------------------------------------------
// combine: sum split partials, divide, blend with last frame.
// ---------------------------------------------------------------------------
__global__ void combine(const float* __restrict__ accP, const float* __restrict__ lP,
                        const float* __restrict__ mv, const float* __restrict__ up,
                        float* __restrict__ out, int split) {
    int idx = blockIdx.x * 256 + threadIdx.x;
    if (idx >= NB * CVD * HWD) return;
    int n = idx % HWD;
    int cv = (idx / HWD) % CVD;
    int b = idx / (HWD * CVD);
    int qblk = n / QB, nl = n % QB;
    size_t base = ((size_t)(b * NQB + qblk) * split) * (CVD * QB) + (size_t)cv * QB + nl;
    size_t lbase = ((size_t)(b * NQB + qblk) * split) * QB + nl;
    float a = 0.f, l = 0.f;
    for (int s = 0; s < split; ++s) {
        a += accP[base + (size_t)s * CVD * QB];
        l += lP[lbase + (size_t)s * QB];
    }
    float ro = a / l;
    float p = up[b * HWD + n];
    float last = mv[((size_t)b * CVD + cv) * THWD + (TD - 1) * HWD + n];
    out[idx] = ro * p + last * (1.f - p);
}

// ---------------------------------------------------------------------------
extern "C" void kernel_launch(void* const* d_in, const int* in_sizes, int n_in,
                              void* d_out, int out_size, void* d_ws,
                              size_t ws_size, hipStream_t stream) {
    const float* qk = (const float*)d_in[0];
    const float* qe = (const float*)d_in[1];
    const float* mk = (const float*)d_in[2];
    const float* ms = (const float*)d_in[3];
    const float* mv = (const float*)d_in[4];
    const float* up = (const float*)d_in[5];
    float* out = (float*)d_out;

    char* ws = (char*)d_ws;
    size_t off = 0;
    auto alloc = [&](size_t bytes) {
        size_t o = off;
        off += (bytes + 255) & ~(size_t)255;
        return o;
    };
    size_t kf_o = alloc((size_t)NB * THWD * 128 * 2);
    size_t qf_o = alloc((size_t)NB * HWD * 128 * 2);
    size_t mvb_o = alloc((size_t)NB * CVD * THWD * 2);
    size_t bsq_o = alloc((size_t)NB * HWD * 4);
    size_t fixed = off;

    size_t per_split = (size_t)NB * NQB * ((size_t)CVD * QB + QB) * 4;
    int split = 16;
    while (split > 1 && fixed + 2 * ((per_split * split + 255) & ~(size_t)255) > ws_size)
        split >>= 1;
    size_t lp_o = alloc((size_t)NB * NQB * split * QB * 4);
    size_t acc_o = alloc((size_t)NB * NQB * split * CVD * QB * 4);

    bf16_t* KFp = (bf16_t*)(ws + kf_o);
    bf16_t* QFp = (bf16_t*)(ws + qf_o);
    bf16_t* MVBp = (bf16_t*)(ws + mvb_o);
    float* bsqp = (float*)(ws + bsq_o);
    float* lPp = (float*)(ws + lp_o);
    float* accPp = (float*)(ws + acc_o);

    int tiles = (THWD / split) / KVB;

    prep_kf<<<dim3(THWD / 64, NB), 256, 0, stream>>>(mk, KFp);
    prep_qf<<<dim3(HWD / 64, NB), 256, 0, stream>>>(qk, qe, QFp, bsqp);
    mv_cvt<<<((size_t)NB * CVD * THWD / 4 + 255) / 256, 256, 0, stream>>>(mv, MVBp);
    fused<<<dim3(NQB, split, NB), 512, 0, stream>>>(KFp, QFp, MVBp, ms, bsqp, accPp,
                                                    lPp, split, tiles);
    combine<<<((size_t)NB * CVD * HWD + 255) / 256, 256, 0, stream>>>(accPp, lPp, mv,
                                                                      up, out, split);
}

// Round 3
// 163.322 us; speedup vs baseline: 8.7902x; 2.3396x over previous
//
#include <hip/hip_runtime.h>
#include <math.h>

// (B, CK, CV, T, H, W) = (2, 64, 256, 8, 48, 48)
#define NB 2
#define CKD 64
#define CVD 256
#define TD 8
#define HWD 2304
#define THWD 18432
#define QB 64
#define NQB (HWD / QB)   // 36
#define KVT 32           // kv per inner tile

typedef __bf16 bf16_t;
typedef __bf16 bf16x8 __attribute__((ext_vector_type(8)));
typedef __bf16 bf16x4 __attribute__((ext_vector_type(4)));
typedef float f32x4 __attribute__((ext_vector_type(4)));
typedef unsigned int u32;

__device__ __forceinline__ void gload16(const void* g, void* l) {
    __builtin_amdgcn_global_load_lds((const __attribute__((address_space(1))) u32*)g,
                                     (__attribute__((address_space(3))) u32*)l, 16, 0, 0);
}

// ---------------------------------------------------------------------------
// prep_kf: KF2 tiled layout. Element (kv, c) with c in [0,128):
//   val = mk[c][kv] (c<64) | mk[c-64][kv]^2 (c>=64)
//   byte = ((b*1152 + kv/16)*16 + kv%16)*256 + ((G ^ (kv&7))<<4) + (c%8)*2,  G=c/8
// ---------------------------------------------------------------------------
__global__ void prep_kf(const float* __restrict__ mk, char* __restrict__ KF2) {
    __shared__ float tile[64][65];
    const int b = blockIdx.y;
    const int kv0 = blockIdx.x * 64;
    const int tid = threadIdx.x;
    {
        const int c = tid >> 2, seg = tid & 3;
        const float* src = mk + ((size_t)b * CKD + c) * THWD + kv0;
#pragma unroll
        for (int j = 0; j < 4; ++j) {
            int ch = seg + j * 4;
            f32x4 v = *(const f32x4*)(src + ch * 4);
#pragma unroll
            for (int x = 0; x < 4; ++x) tile[c][ch * 4 + x] = v[x];
        }
    }
    __syncthreads();
#pragma unroll
    for (int k = 0; k < 4; ++k) {
        int gid = k * 256 + tid;        // 1024 granules: 64 kv x 16 G
        int kvl = gid >> 4, G = gid & 15;
        bf16x8 o;
#pragma unroll
        for (int e = 0; e < 8; ++e) {
            int c = G * 8 + e;
            float v;
            if (c < 64) v = tile[c][kvl];
            else { float m = tile[c - 64][kvl]; v = m * m; }
            o[e] = (bf16_t)v;
        }
        size_t byte = (((size_t)b * 1152 + ((kv0 + kvl) >> 4)) * 16 + (kvl & 15)) * 256 +
                      (size_t)((G ^ (kvl & 7)) << 4);
        *(bf16x8*)(KF2 + byte) = o;
    }
}

// ---------------------------------------------------------------------------
// prep_qf: QF2 tiled: element (q, c): 2*qk*qe (c<64) | -qe (c>=64)
//   byte = (((b*144 + q/16)*4 + c/32)*16 + q%16)*64 + (((c%32)/8)<<4) + (c%8)*2
// bsq[b][q] = sum_c qe*qk*qk (fp32)
// ---------------------------------------------------------------------------
__global__ void prep_qf(const float* __restrict__ qk, const float* __restrict__ qe,
                        char* __restrict__ QF2, float* __restrict__ bsq) {
    __shared__ float tk[64][65];
    __shared__ float te[64][65];
    __shared__ float bs[4][64];
    const int b = blockIdx.y;
    const int q0 = blockIdx.x * 64;
    const int tid = threadIdx.x;
    {
        const int c = tid >> 2, seg = tid & 3;
        const float* s1 = qk + ((size_t)b * CKD + c) * HWD + q0;
        const float* s2 = qe + ((size_t)b * CKD + c) * HWD + q0;
#pragma unroll
        for (int j = 0; j < 4; ++j) {
            int ch = seg + j * 4;
            f32x4 v1 = *(const f32x4*)(s1 + ch * 4);
            f32x4 v2 = *(const f32x4*)(s2 + ch * 4);
#pragma unroll
            for (int x = 0; x < 4; ++x) { tk[c][ch * 4 + x] = v1[x]; te[c][ch * 4 + x] = v2[x]; }
        }
    }
    __syncthreads();
    {   // bsq partials
        int qls = tid & 63, cp = tid >> 6;
        float s = 0.f;
#pragma unroll
        for (int cc = 0; cc < 16; ++cc) {
            int c = cp * 16 + cc;
            float kk = tk[c][qls];
            s = fmaf(te[c][qls] * kk, kk, s);
        }
        bs[cp][qls] = s;
    }
#pragma unroll
    for (int k = 0; k < 4; ++k) {
        int gid = k * 256 + tid;
        int qll = gid >> 4, G = gid & 15;
        int ks = G >> 2, G2 = G & 3;
        bf16x8 o;
#pragma unroll
        for (int e = 0; e < 8; ++e) {
            int c = G * 8 + e;
            float v;
            if (c < 64) v = 2.f * tk[c][qll] * te[c][qll];
            else v = -te[c - 64][qll];
            o[e] = (bf16_t)v;
        }
        size_t byte = ((((size_t)b * 144 + blockIdx.x * 4 + (qll >> 4)) * 4 + ks) * 16 +
                       (qll & 15)) * 64 + (size_t)(G2 << 4);
        *(bf16x8*)(QF2 + byte) = o;
    }
    __syncthreads();
    if (tid < 64) bsq[b * HWD + q0 + tid] = bs[0][tid] + bs[1][tid] + bs[2][tid] + bs[3][tid];
}

// ---------------------------------------------------------------------------
// mv_t: mv fp32 [b][cv][thw] -> mvT bf16 tiled:
//   byte = ((b*576 + kv/32)*256 + cv)*64 + (((kv%32/8) ^ ((cv>>1)&3))<<4) + (kv%8)*2
// ---------------------------------------------------------------------------
__global__ void mv_t(const float* __restrict__ mv, char* __restrict__ mvT) {
    __shared__ float tile[64][65];
    const int b = blockIdx.z;
    const int cv0 = blockIdx.y * 64;
    const int kv0 = blockIdx.x * 64;
    const int tid = threadIdx.x;
    {
        const int cvl = tid >> 2, seg = tid & 3;
        const float* src = mv + ((size_t)b * CVD + cv0 + cvl) * THWD + kv0;
#pragma unroll
        for (int j = 0; j < 4; ++j) {
            int ch = seg + j * 4;
            f32x4 v = *(const f32x4*)(src + ch * 4);
#pragma unroll
            for (int x = 0; x < 4; ++x) tile[cvl][ch * 4 + x] = v[x];
        }
    }
    __syncthreads();
#pragma unroll
    for (int k = 0; k < 2; ++k) {
        int gid = k * 256 + tid;        // 512 granules: 64 cv x 8
        int cvl = gid >> 3, gseg = gid & 7;
        int t32l = gseg >> 2, G = gseg & 3;
        int cv = cv0 + cvl;
        bf16x8 o;
#pragma unroll
        for (int e = 0; e < 8; ++e) o[e] = (bf16_t)tile[cvl][gseg * 8 + e];
        size_t byte = (((size_t)b * 576 + (kv0 >> 5) + t32l) * 256 + cv) * 64 +
                      (size_t)((G ^ ((cv >> 1) & 3)) << 4);
        *(bf16x8*)(mvT + byte) = o;
    }
}

// ---------------------------------------------------------------------------
// fused: 256 thr = 4 waves (wq = wave&1 -> q 32-range, wc = wave>>1 -> cv-half
// and kv 16-strip). Per KVT=32 tile: stage next KF/mv via global_load_lds
// (double buffered, counted waits, raw barriers), QK MFMA, exp, w via swizzled
// LDS, PV MFMA. Split-T partials are plain sums (scores <= 0, no max needed).
// ---------------------------------------------------------------------------
__global__ __launch_bounds__(256, 3) void fused(
    const char* __restrict__ KF2, const char* __restrict__ QF2,
    const char* __restrict__ mvT, const float* __restrict__ ms,
    const float* __restrict__ bsq, float* __restrict__ accP,
    float* __restrict__ lP, int split, int tiles) {
    __shared__ __align__(16) char kf_s[2][8192];
    __shared__ __align__(16) char mv_s[2][16384];
    __shared__ __align__(16) char w_s[4096];
    __shared__ float l_s[2][64];

    const int tid = threadIdx.x;
    const int lane = tid & 63;
    const int wave = tid >> 6;
    const int wq = wave & 1;
    const int wc = wave >> 1;
    const int r = lane & 15;
    const int g = lane >> 4;
    const int swq = (r >> 1) & 3;

    // XCD-clustered decode: same-XCD blocks share a t-range (KF+mv fit 4MB L2)
    const int nwg = gridDim.x;
    const int bid = blockIdx.x;
    const int id = (bid & 7) * (nwg >> 3) + (bid >> 3);
    const int sp = id / 72;
    const int rem = id - sp * 72;
    const int b = rem / 36;
    const int qblk = rem - b * 36;

    const int tbase = sp * (THWD / split);

    const char* KFb = KF2 + (size_t)b * THWD * 256;
    const char* QFb = QF2 + (size_t)b * 144 * 4096;
    const char* mvTb = mvT + (size_t)b * 576 * 16384;
    const float* msb = ms + (size_t)b * THWD;

    // resident query fragments + bsq
    bf16x8 qf[2][4];
    float bsqr[2];
#pragma unroll
    for (int ql = 0; ql < 2; ++ql) {
        int qb16 = qblk * 4 + wq * 2 + ql;
#pragma unroll
        for (int ks = 0; ks < 4; ++ks)
            qf[ql][ks] = *(const bf16x8*)(QFb + ((size_t)qb16 * 4 + ks) * 1024 + r * 64 + g * 16);
        bsqr[ql] = bsq[b * HWD + qblk * 64 + wq * 32 + ql * 16 + r];
    }

    f32x4 acc[8][2];
#pragma unroll
    for (int i = 0; i < 8; ++i)
#pragma unroll
        for (int j = 0; j < 2; ++j) acc[i][j] = (f32x4){0.f, 0.f, 0.f, 0.f};
    float lacc[2] = {0.f, 0.f};

    auto stage = [&](int buf, int t0) {
        const char* gk = KFb + (size_t)(t0 >> 4) * 4096 + wave * 2048 + lane * 16;
        char* lk = &kf_s[buf][wave * 2048];
        gload16(gk, lk);
        gload16(gk + 1024, lk + 1024);
        const char* gm = mvTb + (size_t)(t0 >> 5) * 16384 + wave * 4096 + lane * 16;
        char* lm = &mv_s[buf][wave * 4096];
#pragma unroll
        for (int i = 0; i < 4; ++i) gload16(gm + i * 1024, lm + i * 1024);
    };

    f32x4 msv[2];
    stage(0, tbase);
    msv[0] = *(const f32x4*)(msb + tbase + wc * 16 + g * 4);

#pragma unroll 2
    for (int it = 0; it < tiles; ++it) {
        const int t0 = tbase + it * KVT;
        const char* kf_c = kf_s[it & 1];
        const char* mv_c = mv_s[it & 1];

        // tile fence: staging(it) landed; everyone's reads of buf(it-1)/w_s done
        asm volatile("s_waitcnt vmcnt(0) lgkmcnt(0)" ::: "memory");
        __builtin_amdgcn_s_barrier();

        if (it + 1 < tiles) {   // prefetch next tile (lands during this compute)
            stage((it + 1) & 1, t0 + KVT);
            msv[(it + 1) & 1] = *(const f32x4*)(msb + t0 + KVT + wc * 16 + g * 4);
        }

        // QK: S[ql][i] = score[kv = wc*16 + g*4 + i][q = wq*32 + ql*16 + r]
        f32x4 S[2];
        S[0] = (f32x4){0.f, 0.f, 0.f, 0.f};
        S[1] = (f32x4){0.f, 0.f, 0.f, 0.f};
#pragma unroll
        for (int ks = 0; ks < 4; ++ks) {
            bf16x8 kff = *(const bf16x8*)(kf_c + (wc * 16 + r) * 256 +
                                          (((ks * 4 + g) ^ (r & 7)) << 4));
#pragma unroll
            for (int ql = 0; ql < 2; ++ql)
                S[ql] = __builtin_amdgcn_mfma_f32_16x16x32_bf16(kff, qf[ql][ks], S[ql], 0, 0, 0);
        }

        // exp (scores <= 0: no max bookkeeping), pack bf16, swizzled w_s write
        f32x4 msc = msv[it & 1];
#pragma unroll
        for (int ql = 0; ql < 2; ++ql) {
            int q = wq * 32 + ql * 16 + r;
            f32x4 sv = S[ql];
            float w0 = __expf((sv[0] - bsqr[ql]) * (msc[0] * 0.125f));
            float w1 = __expf((sv[1] - bsqr[ql]) * (msc[1] * 0.125f));
            float w2 = __expf((sv[2] - bsqr[ql]) * (msc[2] * 0.125f));
            float w3 = __expf((sv[3] - bsqr[ql]) * (msc[3] * 0.125f));
            lacc[ql] += (w0 + w1) + (w2 + w3);
            bf16x4 wb;
            wb[0] = (bf16_t)w0; wb[1] = (bf16_t)w1; wb[2] = (bf16_t)w2; wb[3] = (bf16_t)w3;
            *(bf16x4*)(&w_s[q * 64 + (((wc * 2 + (g >> 1)) ^ swq) << 4) + (g & 1) * 8]) = wb;
        }
        asm volatile("s_waitcnt lgkmcnt(0)" ::: "memory");
        __builtin_amdgcn_s_barrier();

        // PV: acc[cv][q] += mv[cv][kv] * w[kv][q]
        bf16x8 wf[2];
#pragma unroll
        for (int ql = 0; ql < 2; ++ql) {
            int q = wq * 32 + ql * 16 + r;
            wf[ql] = *(const bf16x8*)(&w_s[q * 64 + ((g ^ swq) << 4)]);
        }
#pragma unroll
        for (int cvt = 0; cvt < 8; ++cvt) {
            bf16x8 mvf = *(const bf16x8*)(mv_c + (wc * 128 + cvt * 16 + r) * 64 +
                                          ((g ^ swq) << 4));
#pragma unroll
            for (int ql = 0; ql < 2; ++ql)
                acc[cvt][ql] = __builtin_amdgcn_mfma_f32_16x16x32_bf16(mvf, wf[ql], acc[cvt][ql], 0, 0, 0);
        }
    }

    // epilogue: partial acc / l
    size_t pb = (size_t)(b * NQB + qblk) * split + sp;
    float* accB = accP + pb * (CVD * QB);
#pragma unroll
    for (int cvt = 0; cvt < 8; ++cvt)
#pragma unroll
        for (int ql = 0; ql < 2; ++ql) {
            int q = wq * 32 + ql * 16 + r;
#pragma unroll
            for (int i = 0; i < 4; ++i)
                accB[(size_t)(wc * 128 + cvt * 16 + g * 4 + i) * QB + q] = acc[cvt][ql][i];
        }
#pragma unroll
    for (int ql = 0; ql < 2; ++ql) {
        float v = lacc[ql];
        v += __shfl_xor(v, 16);
        v += __shfl_xor(v, 32);
        if (lane < 16) l_s[wc][wq * 32 + ql * 16 + lane] = v;
    }
    __syncthreads();
    if (tid < QB) lP[pb * QB + tid] = l_s[0][tid] + l_s[1][tid];
}

// ---------------------------------------------------------------------------
// combine: sum split partials, divide, blend with last frame (fp32 source).
// ---------------------------------------------------------------------------
__global__ void combine(const float* __restrict__ accP, const float* __restrict__ lP,
                        const float* __restrict__ mv, const float* __restrict__ up,
                        float* __restrict__ out, int split) {
    int idx = blockIdx.x * 256 + threadIdx.x;
    if (idx >= NB * CVD * HWD) return;
    int n = idx % HWD;
    int cv = (idx / HWD) % CVD;
    int b = idx / (HWD * CVD);
    int qblk = n / QB, nl = n % QB;
    size_t base = ((size_t)(b * NQB + qblk) * split) * (CVD * QB) + (size_t)cv * QB + nl;
    size_t lbase = ((size_t)(b * NQB + qblk) * split) * QB + nl;
    float a = 0.f, l = 0.f;
    for (int s = 0; s < split; ++s) {
        a += accP[base + (size_t)s * (CVD * QB)];
        l += lP[lbase + (size_t)s * QB];
    }
    float ro = a / l;
    float p = up[b * HWD + n];
    float last = mv[((size_t)b * CVD + cv) * THWD + (TD - 1) * HWD + n];
    out[idx] = ro * p + last * (1.f - p);
}

// ---------------------------------------------------------------------------
extern "C" void kernel_launch(void* const* d_in, const int* in_sizes, int n_in,
                              void* d_out, int out_size, void* d_ws,
                              size_t ws_size, hipStream_t stream) {
    const float* qk = (const float*)d_in[0];
    const float* qe = (const float*)d_in[1];
    const float* mk = (const float*)d_in[2];
    const float* ms = (const float*)d_in[3];
    const float* mv = (const float*)d_in[4];
    const float* up = (const float*)d_in[5];
    float* out = (float*)d_out;

    char* ws = (char*)d_ws;
    size_t off = 0;
    auto alloc = [&](size_t bytes) {
        size_t o = off;
        off += (bytes + 255) & ~(size_t)255;
        return o;
    };
    size_t kf_o = alloc((size_t)NB * THWD * 256);        // KF2 bf16 tiled
    size_t qf_o = alloc((size_t)NB * 144 * 4096);        // QF2 bf16 tiled
    size_t mvt_o = alloc((size_t)NB * 576 * 16384);      // mvT bf16 tiled
    size_t bsq_o = alloc((size_t)NB * HWD * 4);
    size_t fixed = off;

    int split = 16;
    while (split > 1) {
        size_t need = fixed +
                      (((size_t)NB * NQB * split * CVD * QB * 4 + 255) & ~(size_t)255) +
                      (((size_t)NB * NQB * split * QB * 4 + 255) & ~(size_t)255);
        if (need <= ws_size) break;
        split >>= 1;
    }
    size_t lp_o = alloc((size_t)NB * NQB * split * QB * 4);
    size_t acc_o = alloc((size_t)NB * NQB * split * CVD * QB * 4);

    char* KF2 = ws + kf_o;
    char* QF2 = ws + qf_o;
    char* MVT = ws + mvt_o;
    float* bsqp = (float*)(ws + bsq_o);
    float* lPp = (float*)(ws + lp_o);
    float* accPp = (float*)(ws + acc_o);

    int tiles = (THWD / split) / KVT;

    prep_kf<<<dim3(THWD / 64, NB), 256, 0, stream>>>(mk, KF2);
    prep_qf<<<dim3(HWD / 64, NB), 256, 0, stream>>>(qk, qe, QF2, bsqp);
    mv_t<<<dim3(THWD / 64, CVD / 64, NB), 256, 0, stream>>>(mv, MVT);

    int nwg = NB * NQB * split;   // 72*split, %8==0
    fused<<<nwg, 256, 0, stream>>>(KF2, QF2, MVT, ms, bsqp, accPp, lPp, split, tiles);

    combine<<<((size_t)NB * CVD * HWD + 255) / 256, 256, 0, stream>>>(accPp, lPp, mv,
                                                                      up, out, split);
}